// Round 11
// baseline (42.043 us; speedup 1.0000x reference)
//
#include <hip/hip_runtime.h>
#include <hip/hip_bf16.h>
#include <math.h>

// out[n] = top1(s) - top2(s),  s_c = 2 mu_c.x - ||mu_c||^2
//
// SINGLE fused kernel (511 blocks x 512 thr, 98 rows/block, 1 block/CU):
//  - issue X windows 0,1,2 FIRST (24 global_load_dwordx4/wave in flight =
//    192 KB/CU: HBM stays saturated through the whole prologue; the P1
//    barrier drain waits on USEFUL bytes)
//  - P1: gather-build 64 KB bf16 B-fragment table directly in LDS from
//    fp32 centroids (128 KB, L2/L3-hot; overlapped with X prefetch)
//  - P2: ||mu_c||^2 from the bf16 table (operand-consistent, fp32 accum)
//  - main loop: X streamed as 512B-contiguous row-pair bursts into a
//    wave-PRIVATE 2x4KB XOR-swizzled LDS double buffer; A-frags ds_read
//    from LDS; 4-buffer register prefetch at distance 3; barrier-free
//  - merged shfl_xor top-2 epilogue, one store per row
// A and B use the same k-slot mapping -> dot invariant to slot permutation.

#define KTOT  32
#define DDIM  1024
#define BLK   512
#define RPB   98     // rows per block -> grid 511

typedef __attribute__((ext_vector_type(8))) short short8v;
typedef __attribute__((ext_vector_type(4))) short short4v;
typedef __attribute__((ext_vector_type(4))) float f32x4;

__device__ __forceinline__ short f2bf(float x) {  // RNE; pairs into v_cvt_pk_bf16_f32
  __hip_bfloat16 h = __float2bfloat16(x);
  return __builtin_bit_cast(short, h);
}

__global__ __launch_bounds__(BLK, 2)
void nkm_fused_kernel(const float* __restrict__ X,
                      const float* __restrict__ Cent,
                      float* __restrict__ out, int N) {
  __shared__ short ldsAll[65536];   // 64 KB table + 8 waves x 8 KB X dbuf
  __shared__ float sqPart[BLK];     // 2 KB
  __shared__ float sqArr[KTOT];     // 128 B

  const int tid  = threadIdx.x;
  const int lane = tid & 63;
  const int wid  = tid >> 6;      // wave 0..7
  const int g    = lane >> 4;     // 16-lane group 0..3
  const int cc   = lane & 15;

  short* ldsB = ldsAll;                                  // table (linear, proven)
  char*  xbuf = (char*)&ldsAll[32768] + wid * 8192;      // private 2 x 4096 B

  const int blk_base = blockIdx.x * RPB;
  int limit = blk_base + RPB; if (limit > N) limit = N;
  const int rb = blk_base + wid * 16;

  // ---- loop-invariant row-pair pointers: instr j covers rows {2j, 2j+1},
  //      lane l -> row 2j+(l>>5), bytes (l&31)*16 within the 512B window run
  const float* pj[8];
  #pragma unroll
  for (int j = 0; j < 8; ++j) {
    int r = rb + 2 * j + (lane >> 5);
    if (r >= limit) r = limit - 1;       // clamped dup (cache hit), store off
    pj[j] = X + (size_t)r * DDIM + (lane & 31) * 4;
  }

  // ---- issue X windows 0,1,2 first (24 loads/wave -> 192 KB/CU in flight;
  //      HBM transfers useful stream bytes for the entire prologue)
  f32x4 r0[8], r1[8], r2[8], r3[8];
  #pragma unroll
  for (int j = 0; j < 8; ++j) r0[j] = *(const f32x4*)(pj[j]);
  #pragma unroll
  for (int j = 0; j < 8; ++j) r1[j] = *(const f32x4*)(pj[j] + 128);
  #pragma unroll
  for (int j = 0; j < 8; ++j) r2[j] = *(const f32x4*)(pj[j] + 256);

  // ---- P1: gather-build fragment table. item i: st=i>>6, l=i&63
  #pragma unroll
  for (int j = 0; j < 8; ++j) {
    const int i  = tid + j * BLK;        // 0..4095
    const int l  = i & 63;
    const int st = i >> 6;
    const int col = ((st & 1) << 4) | (l & 15);
    const int d0  = ((st >> 1) << 5) + ((l >> 4) << 3);
    const float* cp = Cent + (size_t)col * DDIM + d0;
    f32x4 f0 = *(const f32x4*)cp;
    f32x4 f1 = *(const f32x4*)(cp + 4);
    short8v v;
    v[0] = f2bf(f0[0]); v[1] = f2bf(f0[1]); v[2] = f2bf(f0[2]); v[3] = f2bf(f0[3]);
    v[4] = f2bf(f1[0]); v[5] = f2bf(f1[1]); v[6] = f2bf(f1[2]); v[7] = f2bf(f1[3]);
    *(short8v*)&ldsB[(size_t)i * 8] = v;
  }
  __syncthreads();

  // ---- P2: ||mu_c||^2 from bf16 frags (16 segs x 64 dims per col)
  {
    const int c = tid & 31, seg = tid >> 5;
    float s = 0.f;
    #pragma unroll
    for (int q = 0; q < 8; ++q) {
      const int d    = seg * 64 + q * 8;
      const int item = ((d >> 5) << 1) | (c >> 4);
      const int fl   = (c & 15) | (((d >> 3) & 3) << 4);
      short8v b = *(const short8v*)&ldsB[(size_t)(item * 64 + fl) * 8];
      #pragma unroll
      for (int e = 0; e < 8; ++e) {
        float bv = __uint_as_float(((unsigned)(unsigned short)b[e]) << 16);
        s = fmaf(bv, bv, s);
      }
    }
    sqPart[seg * 32 + c] = s;
  }
  __syncthreads();
  if (tid < KTOT) {
    float s = 0.f;
    #pragma unroll
    for (int j = 0; j < 16; ++j) s += sqPart[j * 32 + tid];
    sqArr[tid] = s;
  }
  __syncthreads();

  const float sq0 = sqArr[cc];
  const float sq1 = sqArr[cc + 16];

  if (rb >= limit) return;        // idle waves exit after all barriers

  // staging/store address pieces
  const int wb0 = ((lane >> 5) << 8) + (lane & 31) * 8;  // row-half*256 + col*8

  // A-frag read offsets (per k-substep s'), swizzled: row=cc, slot=s'*4+g
  int raddr[4];
  #pragma unroll
  for (int sp = 0; sp < 4; ++sp) {
    int a = cc * 256 + (sp * 4 + g) * 16;
    raddr[sp] = a ^ (((a >> 8) & 0xF) << 4);
  }

  f32x4 acc0 = {0.f, 0.f, 0.f, 0.f};
  f32x4 acc1 = {0.f, 0.f, 0.f, 0.f};

  #pragma unroll
  for (int w = 0; w < 8; ++w) {               // 8 windows x 128 dims
    // static 4-buffer rotation (full unroll -> registers, rule #20)
    f32x4* curb = (w % 4 == 0) ? r0 : (w % 4 == 1) ? r1 : (w % 4 == 2) ? r2 : r3;
    f32x4* preb = ((w + 3) % 4 == 0) ? r0 : ((w + 3) % 4 == 1) ? r1
                : ((w + 3) % 4 == 2) ? r2 : r3;
    // prefetch window w+3 (keeps ~24KB/wave outstanding at all times)
    if (w < 5) {
      #pragma unroll
      for (int j = 0; j < 8; ++j) preb[j] = *(const f32x4*)(pj[j] + (w + 3) * 128);
    }
    // stage current window into private LDS (bf16, swizzled)
    char* bp = xbuf + (w & 1) * 4096;
    #pragma unroll
    for (int j = 0; j < 8; ++j) {
      int wb = wb0 + j * 512;
      wb ^= ((wb >> 8) & 0xF) << 4;
      f32x4 v = curb[j];
      short4v pk;
      pk[0] = f2bf(v[0]); pk[1] = f2bf(v[1]); pk[2] = f2bf(v[2]); pk[3] = f2bf(v[3]);
      *(short4v*)(bp + wb) = pk;
    }
    // 4 k-steps: A from private LDS, B from table, 2 MFMA chains
    #pragma unroll
    for (int sp = 0; sp < 4; ++sp) {
      const int s = w * 4 + sp;
      const short8v a  = *(const short8v*)(bp + raddr[sp]);
      const short8v b0 = *(const short8v*)&ldsB[(size_t)(((s << 1) | 0) * 64 + lane) * 8];
      const short8v b1 = *(const short8v*)&ldsB[(size_t)(((s << 1) | 1) * 64 + lane) * 8];
      acc0 = __builtin_amdgcn_mfma_f32_16x16x32_bf16(a, b0, acc0, 0, 0, 0);
      acc1 = __builtin_amdgcn_mfma_f32_16x16x32_bf16(a, b1, acc1, 0, 0, 0);
    }
  }

  // ---- epilogue: s = 2*dot - sq; top-2 across 16 lanes x 2 cols each
  const int rbase = rb + (g << 2);
  #pragma unroll
  for (int r = 0; r < 4; ++r) {
    float v0 = fmaf(2.f, acc0[r], -sq0);
    float v1 = fmaf(2.f, acc1[r], -sq1);
    float m1 = fmaxf(v0, v1);
    float m2 = fminf(v0, v1);
    #pragma unroll
    for (int d = 1; d <= 8; d <<= 1) {
      float om1 = __shfl_xor(m1, d, 64);
      float om2 = __shfl_xor(m2, d, 64);
      m2 = fmaxf(fmaxf(fminf(m1, om1), om2), m2);  // merged top-2
      m1 = fmaxf(m1, om1);
    }
    const int orow = rbase + r;
    if (cc == 0 && orow < limit) out[orow] = m1 - m2;
  }
}

extern "C" void kernel_launch(void* const* d_in, const int* in_sizes, int n_in,
                              void* d_out, int out_size, void* d_ws, size_t ws_size,
                              hipStream_t stream) {
  const float* X = (const float*)d_in[0];
  const float* C = (const float*)d_in[1];
  float* out = (float*)d_out;
  const int N = in_sizes[0] / DDIM;            // 50000
  const int blocks = (N + RPB - 1) / RPB;      // 511
  hipLaunchKernelGGL(nkm_fused_kernel, dim3(blocks), dim3(BLK), 0, stream,
                     X, C, out, N);
}

// Round 12
// 38.347 us; speedup vs baseline: 1.0964x; 1.0964x over previous
//
#include <hip/hip_runtime.h>
#include <hip/hip_bf16.h>
#include <math.h>

// out[n] = top1(s) - top2(s),  s_c = 2 mu_c.x - ||mu_c||^2
//
// K-SPLIT redesign, single kernel (511 blocks x 512 thr, 98 rows/block,
// 2 blocks/CU, 4 waves/SIMD):
//  - wave w owns K-dims [128w, 128w+128) of ALL 98 block rows
//  - B-fragments (32 cols x 128 dims bf16) live ENTIRELY in 32 VGPRs/lane:
//    no 64 KB LDS table, no table staging
//  - per 16-row tile: X staged as 512B-contiguous row-pair bursts into a
//    wave-private 4 KB XOR-swizzled LDS buffer (round-6 proven layout),
//    4 k-steps x {ds_read_b128 A + 2 MFMA}, partial 16x32 scores to LDS,
//    barrier, deterministic 8-wave reduce + fused top-2 (512 thr = 16x32),
//    barrier. 2 barriers/tile; co-resident block covers HBM in sync gaps.
//  - sq: from the same bf16 B-regs (operand-consistent), shfl + LDS reduce
// A and B use the same k-slot mapping -> dot invariant to slot permutation.

#define KTOT  32
#define DDIM  1024
#define BLK   512
#define RPB   98
#define TILES 7      // ceil(98/16)

typedef __attribute__((ext_vector_type(8))) short short8v;
typedef __attribute__((ext_vector_type(4))) short short4v;
typedef __attribute__((ext_vector_type(4))) float f32x4;

__device__ __forceinline__ short f2bf(float x) {  // RNE; pairs into v_cvt_pk_bf16_f32
  __hip_bfloat16 h = __float2bfloat16(x);
  return __builtin_bit_cast(short, h);
}
__device__ __forceinline__ float bf2f(short b) {
  return __uint_as_float(((unsigned)(unsigned short)b) << 16);
}

__global__ __launch_bounds__(BLK, 4)
void nkm_ksplit_kernel(const float* __restrict__ X,
                       const float* __restrict__ Cent,
                       float* __restrict__ out, int N) {
  __shared__ short ldsX[16384];    // 32 KB: 8 waves x 4 KB X-stage
  __shared__ float ldsP[4096];     // 16 KB: [8 waves][16 rows][32 cols]
  __shared__ float sqP[256];       // 1 KB : [8 waves][32 cols]
  __shared__ float sqArr[KTOT];    // 128 B

  const int tid  = threadIdx.x;
  const int lane = tid & 63;
  const int wid  = tid >> 6;       // wave 0..7 = K-slice owner
  const int g    = lane >> 4;      // 16-lane group 0..3
  const int cc   = lane & 15;
  const int kw0  = wid << 7;       // this wave's K-offset (dims)

  const int blk_base = blockIdx.x * RPB;
  int limit = blk_base + RPB; if (limit > N) limit = N;

  // ---- issue tile-0 X loads FIRST (row-pair 512B bursts, proven pattern)
  //      instr j: rows {2j,2j+1}, lane l -> row 2j+(l>>5), dim kw0+(l&31)*4
  f32x4 nxt[8];
  #pragma unroll
  for (int j = 0; j < 8; ++j) {
    int r = blk_base + 2 * j + (lane >> 5);
    if (r >= limit) r = limit - 1;
    nxt[j] = *(const f32x4*)(X + (size_t)r * DDIM + kw0 + (lane & 31) * 4);
  }

  // ---- gather B-fragments into registers (16 KB fp32 per wave, L2/L3-hot)
  //      frag (sp,h): col = cc+16h, dims kw0 + sp*32 + g*8 (.. +7)
  short8v bfrag[4][2];
  float psq0 = 0.f, psq1 = 0.f;
  #pragma unroll
  for (int sp = 0; sp < 4; ++sp) {
    #pragma unroll
    for (int h = 0; h < 2; ++h) {
      const int col = cc + (h << 4);
      const float* cp = Cent + (size_t)col * DDIM + kw0 + sp * 32 + (g << 3);
      f32x4 f0 = *(const f32x4*)cp;
      f32x4 f1 = *(const f32x4*)(cp + 4);
      short8v v;
      v[0] = f2bf(f0[0]); v[1] = f2bf(f0[1]); v[2] = f2bf(f0[2]); v[3] = f2bf(f0[3]);
      v[4] = f2bf(f1[0]); v[5] = f2bf(f1[1]); v[6] = f2bf(f1[2]); v[7] = f2bf(f1[3]);
      bfrag[sp][h] = v;
      float s = 0.f;
      #pragma unroll
      for (int e = 0; e < 8; ++e) { float bv = bf2f(v[e]); s = fmaf(bv, bv, s); }
      if (h == 0) psq0 += s; else psq1 += s;
    }
  }
  // reduce sq over the 4 g-groups (lanes differing in bits 4..5)
  psq0 += __shfl_xor(psq0, 16, 64);  psq0 += __shfl_xor(psq0, 32, 64);
  psq1 += __shfl_xor(psq1, 16, 64);  psq1 += __shfl_xor(psq1, 32, 64);
  if (g == 0 && (lane >> 5) == 0) {  // lanes 0..15
    sqP[wid * 32 + cc]      = psq0;
    sqP[wid * 32 + 16 + cc] = psq1;
  }
  __syncthreads();
  if (tid < KTOT) {
    float s = 0.f;
    #pragma unroll
    for (int wv = 0; wv < 8; ++wv) s += sqP[wv * 32 + tid];
    sqArr[tid] = s;   // visible to all after tile-0's first barrier
  }

  // ---- per-wave LDS addresses (round-6 proven swizzle)
  char* ldsXb = (char*)ldsX + wid * 4096;
  const int wb0 = ((lane >> 5) << 8) + (lane & 31) * 8;  // row-half*256 + col*8
  int raddr[4];
  #pragma unroll
  for (int sp = 0; sp < 4; ++sp) {
    int a = cc * 256 + (sp * 4 + g) * 16;
    raddr[sp] = a ^ (((a >> 8) & 0xF) << 4);
  }

  // ---- main: 7 tiles of 16 rows
  #pragma unroll
  for (int t = 0; t < TILES; ++t) {
    // stage tile t (bf16, swizzled) into the wave-private buffer
    #pragma unroll
    for (int j = 0; j < 8; ++j) {
      int wb = wb0 + j * 512;
      wb ^= ((wb >> 8) & 0xF) << 4;
      f32x4 v = nxt[j];
      short4v pk;
      pk[0] = f2bf(v[0]); pk[1] = f2bf(v[1]); pk[2] = f2bf(v[2]); pk[3] = f2bf(v[3]);
      *(short4v*)(ldsXb + wb) = pk;
    }
    // issue tile t+1 loads (overlap with MFMA + reduce below)
    if (t < TILES - 1) {
      const int rbn = blk_base + (t + 1) * 16;
      #pragma unroll
      for (int j = 0; j < 8; ++j) {
        int r = rbn + 2 * j + (lane >> 5);
        if (r >= limit) r = limit - 1;
        nxt[j] = *(const f32x4*)(X + (size_t)r * DDIM + kw0 + (lane & 31) * 4);
      }
    }
    // 4 k-steps: A from LDS, B from registers
    f32x4 acc0 = {0.f, 0.f, 0.f, 0.f};
    f32x4 acc1 = {0.f, 0.f, 0.f, 0.f};
    #pragma unroll
    for (int sp = 0; sp < 4; ++sp) {
      const short8v a = *(const short8v*)(ldsXb + raddr[sp]);
      acc0 = __builtin_amdgcn_mfma_f32_16x16x32_bf16(a, bfrag[sp][0], acc0, 0, 0, 0);
      acc1 = __builtin_amdgcn_mfma_f32_16x16x32_bf16(a, bfrag[sp][1], acc1, 0, 0, 0);
    }
    // partial scores -> LDS [wid][row][col]
    #pragma unroll
    for (int r = 0; r < 4; ++r) {
      const int rw = (g << 2) + r;
      ldsP[wid * 512 + rw * 32 + cc]      = acc0[r];
      ldsP[wid * 512 + rw * 32 + 16 + cc] = acc1[r];
    }
    __syncthreads();
    // deterministic 8-wave reduce + fused top-2 (thread = (row, col))
    {
      const int row = tid >> 5, col = tid & 31;
      float v = 0.f;
      #pragma unroll
      for (int wv = 0; wv < 8; ++wv) v += ldsP[wv * 512 + row * 32 + col];
      float s = fmaf(2.f, v, -sqArr[col]);
      float m1 = s, m2 = -INFINITY;
      #pragma unroll
      for (int d = 1; d <= 16; d <<= 1) {
        float o1 = __shfl_xor(m1, d, 64);
        float o2 = __shfl_xor(m2, d, 64);
        m2 = fmaxf(fmaxf(fminf(m1, o1), o2), m2);  // merged top-2
        m1 = fmaxf(m1, o1);
      }
      const int orow = blk_base + t * 16 + row;
      if ((tid & 31) == 0 && orow < limit) out[orow] = m1 - m2;
    }
    __syncthreads();   // protect ldsP before next tile's partial writes
  }
}

extern "C" void kernel_launch(void* const* d_in, const int* in_sizes, int n_in,
                              void* d_out, int out_size, void* d_ws, size_t ws_size,
                              hipStream_t stream) {
  const float* X = (const float*)d_in[0];
  const float* C = (const float*)d_in[1];
  float* out = (float*)d_out;
  const int N = in_sizes[0] / DDIM;            // 50000
  const int blocks = (N + RPB - 1) / RPB;      // 511
  hipLaunchKernelGGL(nkm_ksplit_kernel, dim3(blocks), dim3(BLK), 0, stream,
                     X, C, out, N);
}

// Round 13
// 38.245 us; speedup vs baseline: 1.0993x; 1.0027x over previous
//
#include <hip/hip_runtime.h>
#include <hip/hip_bf16.h>
#include <math.h>

// out[n] = top1(s) - top2(s),  s_c = 2 mu_c.x - ||mu_c||^2
//
// K-SPLIT kernel (511 blocks x 512 thr, 98 rows/block, 2 blocks/CU):
//  - wave w owns K-dims [128w, 128w+128); B-frags (32 cols x 128 dims bf16)
//    entirely in 32 VGPRs/lane; no LDS B-table
//  - per 16-row tile: X staged as 512B-contiguous row-pair bursts into a
//    wave-private 4 KB XOR-swizzled LDS buffer; 4 k-steps {ds_read_b128 A +
//    2 MFMA}; partials -> double-buffered ldsP[t&1] (row-XOR col swizzle,
//    2-way max); then ONE raw barrier per tile:
//        s_waitcnt lgkmcnt(0); s_barrier
//    -- vmcnt is NEVER drained in the main loop, so next-tile X loads stay
//    in flight across the barrier (the round-12 __syncthreads pair drained
//    vmcnt(0) twice per tile, collapsing prefetch distance).
//  - deterministic 8-wave reduce + fused top-2 after the barrier.
// A and B use the same k-slot mapping -> dot invariant to slot permutation.

#define KTOT  32
#define DDIM  1024
#define BLK   512
#define RPB   98
#define TILES 7      // ceil(98/16)

typedef __attribute__((ext_vector_type(8))) short short8v;
typedef __attribute__((ext_vector_type(4))) short short4v;
typedef __attribute__((ext_vector_type(4))) float f32x4;

__device__ __forceinline__ short f2bf(float x) {  // RNE; pairs into v_cvt_pk_bf16_f32
  __hip_bfloat16 h = __float2bfloat16(x);
  return __builtin_bit_cast(short, h);
}
__device__ __forceinline__ float bf2f(short b) {
  return __uint_as_float(((unsigned)(unsigned short)b) << 16);
}

__global__ __launch_bounds__(BLK, 4)
void nkm_ksplit_kernel(const float* __restrict__ X,
                       const float* __restrict__ Cent,
                       float* __restrict__ out, int N) {
  __shared__ short ldsX[16384];    // 32 KB: 8 waves x 4 KB X-stage (wave-private)
  __shared__ float ldsP[2][4096];  // 2 x 16 KB: [buf][8 waves][16 rows][32 cols]
  __shared__ float sqP[256];       // 1 KB : [8 waves][32 cols]
  __shared__ float sqArr[KTOT];    // 128 B

  const int tid  = threadIdx.x;
  const int lane = tid & 63;
  const int wid  = tid >> 6;       // wave 0..7 = K-slice owner
  const int g    = lane >> 4;      // 16-lane group 0..3
  const int cc   = lane & 15;
  const int kw0  = wid << 7;       // this wave's K-offset (dims)

  const int blk_base = blockIdx.x * RPB;
  int limit = blk_base + RPB; if (limit > N) limit = N;

  // ---- issue tile-0 X loads FIRST (row-pair 512B bursts, proven pattern)
  f32x4 nxt[8];
  #pragma unroll
  for (int j = 0; j < 8; ++j) {
    int r = blk_base + 2 * j + (lane >> 5);
    if (r >= limit) r = limit - 1;
    nxt[j] = *(const f32x4*)(X + (size_t)r * DDIM + kw0 + (lane & 31) * 4);
  }

  // ---- gather B-fragments into registers (16 KB fp32 per wave, L2/L3-hot)
  short8v bfrag[4][2];
  float psq0 = 0.f, psq1 = 0.f;
  #pragma unroll
  for (int sp = 0; sp < 4; ++sp) {
    #pragma unroll
    for (int h = 0; h < 2; ++h) {
      const int col = cc + (h << 4);
      const float* cp = Cent + (size_t)col * DDIM + kw0 + sp * 32 + (g << 3);
      f32x4 f0 = *(const f32x4*)cp;
      f32x4 f1 = *(const f32x4*)(cp + 4);
      short8v v;
      v[0] = f2bf(f0[0]); v[1] = f2bf(f0[1]); v[2] = f2bf(f0[2]); v[3] = f2bf(f0[3]);
      v[4] = f2bf(f1[0]); v[5] = f2bf(f1[1]); v[6] = f2bf(f1[2]); v[7] = f2bf(f1[3]);
      bfrag[sp][h] = v;
      float s = 0.f;
      #pragma unroll
      for (int e = 0; e < 8; ++e) { float bv = bf2f(v[e]); s = fmaf(bv, bv, s); }
      if (h == 0) psq0 += s; else psq1 += s;
    }
  }
  psq0 += __shfl_xor(psq0, 16, 64);  psq0 += __shfl_xor(psq0, 32, 64);
  psq1 += __shfl_xor(psq1, 16, 64);  psq1 += __shfl_xor(psq1, 32, 64);
  if (g == 0 && (lane >> 5) == 0) {  // lanes 0..15
    sqP[wid * 32 + cc]      = psq0;
    sqP[wid * 32 + 16 + cc] = psq1;
  }
  __syncthreads();
  if (tid < KTOT) {
    float s = 0.f;
    #pragma unroll
    for (int wv = 0; wv < 8; ++wv) s += sqP[wv * 32 + tid];
    sqArr[tid] = s;   // visible to all after tile-0's barrier (lgkmcnt(0))
  }

  // ---- per-wave LDS addresses (round-6 proven swizzle for the X stage)
  char* ldsXb = (char*)ldsX + wid * 4096;
  const int wb0 = ((lane >> 5) << 8) + (lane & 31) * 8;  // row-half*256 + col*8
  int raddr[4];
  #pragma unroll
  for (int sp = 0; sp < 4; ++sp) {
    int a = cc * 256 + (sp * 4 + g) * 16;
    raddr[sp] = a ^ (((a >> 8) & 0xF) << 4);
  }

  // ---- main: 7 tiles of 16 rows, ONE raw barrier per tile
  #pragma unroll
  for (int t = 0; t < TILES; ++t) {
    // stage tile t (bf16, swizzled) into the wave-private buffer
    #pragma unroll
    for (int j = 0; j < 8; ++j) {
      int wb = wb0 + j * 512;
      wb ^= ((wb >> 8) & 0xF) << 4;
      f32x4 v = nxt[j];
      short4v pk;
      pk[0] = f2bf(v[0]); pk[1] = f2bf(v[1]); pk[2] = f2bf(v[2]); pk[3] = f2bf(v[3]);
      *(short4v*)(ldsXb + wb) = pk;
    }
    // issue tile t+1 loads; they stay in flight ACROSS the raw barrier
    if (t < TILES - 1) {
      const int rbn = blk_base + (t + 1) * 16;
      #pragma unroll
      for (int j = 0; j < 8; ++j) {
        int r = rbn + 2 * j + (lane >> 5);
        if (r >= limit) r = limit - 1;
        nxt[j] = *(const f32x4*)(X + (size_t)r * DDIM + kw0 + (lane & 31) * 4);
      }
    }
    // 4 k-steps: A from LDS, B from registers
    f32x4 acc0 = {0.f, 0.f, 0.f, 0.f};
    f32x4 acc1 = {0.f, 0.f, 0.f, 0.f};
    #pragma unroll
    for (int sp = 0; sp < 4; ++sp) {
      const short8v a = *(const short8v*)(ldsXb + raddr[sp]);
      acc0 = __builtin_amdgcn_mfma_f32_16x16x32_bf16(a, bfrag[sp][0], acc0, 0, 0, 0);
      acc1 = __builtin_amdgcn_mfma_f32_16x16x32_bf16(a, bfrag[sp][1], acc1, 0, 0, 0);
    }
    // partials -> ldsP[t&1], row-XOR col swizzle (writes/reads <=2-way)
    {
      float* Pw = &ldsP[t & 1][wid * 512];
      #pragma unroll
      for (int r = 0; r < 4; ++r) {
        const int row = (g << 2) + r;
        const int m = (row & 7) << 2;
        Pw[row * 32 + (cc ^ m)]        = acc0[r];
        Pw[row * 32 + ((cc + 16) ^ m)] = acc1[r];
      }
    }
    // ONE raw barrier: LDS visible, global loads stay outstanding
    asm volatile("s_waitcnt lgkmcnt(0)" ::: "memory");
    __builtin_amdgcn_s_barrier();
    asm volatile("" ::: "memory");
    // deterministic 8-wave reduce + fused top-2 (thread = (row, col))
    {
      const int row = tid >> 5, col = tid & 31;
      const int m = (row & 7) << 2;
      const float* Pr = &ldsP[t & 1][row * 32 + (col ^ m)];
      float v = 0.f;
      #pragma unroll
      for (int wv = 0; wv < 8; ++wv) v += Pr[wv * 512];
      float s = fmaf(2.f, v, -sqArr[col]);
      float m1 = s, m2 = -INFINITY;
      #pragma unroll
      for (int d = 1; d <= 16; d <<= 1) {
        float o1 = __shfl_xor(m1, d, 64);
        float o2 = __shfl_xor(m2, d, 64);
        m2 = fmaxf(fmaxf(fminf(m1, o1), o2), m2);  // merged top-2
        m1 = fmaxf(m1, o1);
      }
      const int orow = blk_base + t * 16 + row;
      if ((tid & 31) == 0 && orow < limit) out[orow] = m1 - m2;
    }
    // no second barrier: next tile writes ldsP[(t+1)&1] and private ldsX
  }
}

extern "C" void kernel_launch(void* const* d_in, const int* in_sizes, int n_in,
                              void* d_out, int out_size, void* d_ws, size_t ws_size,
                              hipStream_t stream) {
  const float* X = (const float*)d_in[0];
  const float* C = (const float*)d_in[1];
  float* out = (float*)d_out;
  const int N = in_sizes[0] / DDIM;            // 50000
  const int blocks = (N + RPB - 1) / RPB;      // 511
  hipLaunchKernelGGL(nkm_ksplit_kernel, dim3(blocks), dim3(BLK), 0, stream,
                     X, C, out, N);
}